// Round 1
// baseline (4215.853 us; speedup 1.0000x reference)
//
#include <hip/hip_runtime.h>
#include <hip/hip_cooperative_groups.h>
#include <math.h>

namespace cg = cooperative_groups;

// B=4, T=32, N=32, F=16, GH=64, LH=128
#define T_STEPS 32
#define NNODES  32
#define FEAT    16
#define GHID    64
#define LSTM_IN 2048   // N*GH
#define LSTM_H  4096   // N*LH
#define GATES   16384  // 4*LSTM_H
#define BT      128    // B*T

typedef __attribute__((ext_vector_type(8))) short bhalf8;
typedef __attribute__((ext_vector_type(4))) float floatx4;

__device__ __forceinline__ float sigmoidf_(float x) { return 1.0f / (1.0f + __expf(-x)); }

// fp32 -> bf16 (RNE)
__device__ __forceinline__ unsigned short f2bf(float f) {
    unsigned int u = __float_as_uint(f);
    u += 0x7FFFu + ((u >> 16) & 1u);
    return (unsigned short)(u >> 16);
}

// ------------------------------------------------- dense normalized adjacency
__global__ void build_adj(const int* __restrict__ ei, int E, float* __restrict__ A) {
    __shared__ float As[NNODES * NNODES];
    __shared__ int   deg[NNODES];
    __shared__ float dinv[NNODES];
    int tid = threadIdx.x;
    if (tid < NNODES) deg[tid] = 1;
    for (int i = tid; i < NNODES * NNODES; i += 256) As[i] = 0.0f;
    __syncthreads();
    for (int e = tid; e < E; e += 256) atomicAdd(&deg[ei[E + e]], 1);
    __syncthreads();
    if (tid < NNODES) dinv[tid] = rsqrtf((float)deg[tid]);
    __syncthreads();
    for (int e = tid; e < E; e += 256) {
        int s = ei[e], d = ei[E + e];
        atomicAdd(&As[d * NNODES + s], dinv[s] * dinv[d]);
    }
    if (tid < NNODES) atomicAdd(&As[tid * NNODES + tid], dinv[tid] * dinv[tid]);
    __syncthreads();
    for (int i = tid; i < NNODES * NNODES; i += 256) A[i] = As[i];
}

// ------------------------------------------- LN + GCN1 + GCN2, one block/(b,t)
__global__ __launch_bounds__(256) void gcn2_kernel(
    const float* __restrict__ x, const float* __restrict__ ln_g, const float* __restrict__ ln_b,
    const float* __restrict__ W1, const float* __restrict__ b1,
    const float* __restrict__ W2, const float* __restrict__ b2,
    const float* __restrict__ A, float* __restrict__ seq)
{
    __shared__ float As[NNODES * NNODES];
    __shared__ float w1[FEAT * GHID];
    __shared__ float w2[GHID * GHID];
    __shared__ float xln[NNODES * FEAT];
    __shared__ float h1[NNODES * GHID];
    __shared__ float g1[NNODES * GHID];
    __shared__ float h2[NNODES * GHID];

    int tid = threadIdx.x;
    int bt = blockIdx.x;
    const float* xb = x + (size_t)bt * NNODES * FEAT;

    for (int i = tid; i < 1024; i += 256) As[i] = A[i];
    for (int i = tid; i < FEAT * GHID; i += 256) w1[i] = W1[i];
    for (int i = tid; i < GHID * GHID; i += 256) w2[i] = W2[i];
    for (int i = tid; i < NNODES * FEAT; i += 256) xln[i] = xb[i];
    __syncthreads();

    if (tid < NNODES) {
        float mu = 0.0f;
        for (int f = 0; f < FEAT; ++f) mu += xln[tid * FEAT + f];
        mu *= (1.0f / FEAT);
        float var = 0.0f;
        for (int f = 0; f < FEAT; ++f) { float d = xln[tid * FEAT + f] - mu; var += d * d; }
        var *= (1.0f / FEAT);
        float r = rsqrtf(var + 1e-5f);
        for (int f = 0; f < FEAT; ++f)
            xln[tid * FEAT + f] = (xln[tid * FEAT + f] - mu) * r * ln_g[f] + ln_b[f];
    }
    __syncthreads();

    for (int idx = tid; idx < NNODES * GHID; idx += 256) {
        int n = idx >> 6, j = idx & 63;
        float s = 0.0f;
        #pragma unroll
        for (int f = 0; f < FEAT; ++f) s += xln[n * FEAT + f] * w1[f * GHID + j];
        h1[idx] = s;
    }
    __syncthreads();
    for (int idx = tid; idx < NNODES * GHID; idx += 256) {
        int n = idx >> 6, j = idx & 63;
        float s = b1[j];
        #pragma unroll 8
        for (int m = 0; m < NNODES; ++m) s += As[n * NNODES + m] * h1[m * GHID + j];
        g1[idx] = s;
    }
    __syncthreads();
    for (int idx = tid; idx < NNODES * GHID; idx += 256) {
        int n = idx >> 6, j = idx & 63;
        float s = 0.0f;
        #pragma unroll 8
        for (int k = 0; k < GHID; ++k) s += g1[n * GHID + k] * w2[k * GHID + j];
        h2[idx] = s;
    }
    __syncthreads();
    for (int idx = tid; idx < NNODES * GHID; idx += 256) {
        int n = idx >> 6, j = idx & 63;
        float s = b2[j];
        #pragma unroll 8
        for (int m = 0; m < NNODES; ++m) s += As[n * NNODES + m] * h2[m * GHID + j];
        seq[(size_t)bt * LSTM_IN + idx] = s;
    }
}

// ---------------------------------- x_proj partials via MFMA, fused fp32->bf16
__global__ __launch_bounds__(256) void xproj_mfma(
    const float* __restrict__ seq, const float* __restrict__ W_ih,
    float* __restrict__ xpart)
{
    int lane = threadIdx.x & 63;
    int wid = blockIdx.x * 4 + (threadIdx.x >> 6);  // 0..4095
    int ntile = wid >> 2;                            // 0..1023
    int kc = wid & 3;                                // 0..3
    int n0 = ntile << 4;
    int rr = lane & 15;
    int kg = lane >> 4;

    floatx4 acc[8];
    #pragma unroll
    for (int mt = 0; mt < 8; ++mt) acc[mt] = (floatx4){0.f, 0.f, 0.f, 0.f};

    for (int ks = 0; ks < 16; ++ks) {
        int k0 = (kc << 9) + (ks << 5) + (kg << 3);
        const float4* wp = (const float4*)(W_ih + (size_t)(n0 + rr) * LSTM_IN + k0);
        float4 w0 = wp[0], w1 = wp[1];
        bhalf8 bf;
        bf[0] = (short)f2bf(w0.x); bf[1] = (short)f2bf(w0.y);
        bf[2] = (short)f2bf(w0.z); bf[3] = (short)f2bf(w0.w);
        bf[4] = (short)f2bf(w1.x); bf[5] = (short)f2bf(w1.y);
        bf[6] = (short)f2bf(w1.z); bf[7] = (short)f2bf(w1.w);
        #pragma unroll
        for (int mt = 0; mt < 8; ++mt) {
            const float4* ap = (const float4*)(seq + (size_t)(mt * 16 + rr) * LSTM_IN + k0);
            float4 a0 = ap[0], a1 = ap[1];
            bhalf8 af;
            af[0] = (short)f2bf(a0.x); af[1] = (short)f2bf(a0.y);
            af[2] = (short)f2bf(a0.z); af[3] = (short)f2bf(a0.w);
            af[4] = (short)f2bf(a1.x); af[5] = (short)f2bf(a1.y);
            af[6] = (short)f2bf(a1.z); af[7] = (short)f2bf(a1.w);
            acc[mt] = __builtin_amdgcn_mfma_f32_16x16x32_bf16(af, bf, acc[mt], 0, 0, 0);
        }
    }
    float* xo = xpart + (size_t)kc * (BT * GATES);
    #pragma unroll
    for (int mt = 0; mt < 8; ++mt) {
        #pragma unroll
        for (int i = 0; i < 4; ++i) {
            int row = mt * 16 + kg * 4 + i;
            xo[(size_t)row * GATES + n0 + rr] = acc[mt][i];
        }
    }
}

// -------------------------------- combine 4 K-partials + bias -> xp
__global__ void combine_xp(const float* __restrict__ xpart,
                           const float* __restrict__ b_ih, const float* __restrict__ b_hh,
                           float* __restrict__ xp)
{
    int i = blockIdx.x * 256 + threadIdx.x;
    const float4* p0 = (const float4*)xpart;
    const float4* p1 = p0 + (BT * GATES / 4);
    const float4* p2 = p1 + (BT * GATES / 4);
    const float4* p3 = p2 + (BT * GATES / 4);
    float4 a = p0[i], b = p1[i], c = p2[i], d = p3[i];
    int col = (i & (GATES / 4 - 1)) << 2;
    float4 o;
    o.x = a.x + b.x + c.x + d.x + b_ih[col + 0] + b_hh[col + 0];
    o.y = a.y + b.y + c.y + d.y + b_ih[col + 1] + b_hh[col + 1];
    o.z = a.z + b.z + c.z + d.z + b_ih[col + 2] + b_hh[col + 2];
    o.w = a.w + b.w + c.w + d.w + b_ih[col + 3] + b_hh[col + 3];
    ((float4*)xp)[i] = o;
}

// -------------------------------------------------- persistent LSTM recurrence
// 256 blocks x 1024 threads (1 block/CU, 4 waves/SIMD). The ENTIRE W_hh (128 MB
// bf16) lives in VGPRs as MFMA B-fragments: 4096 waves x 32 bhalf8 (128 VGPRs).
// Block b owns j in [16b,16b+16) for all 4 gates; wave w: gate=w>>2, Ksplit=w&3
// (K range 1024 -> 32 MFMAs/step). Per step: MFMA partials -> LDS split-K
// reduce -> wave0 computes gates/c/h (c kept in wave0 registers) -> one
// grid.sync(). h ping-pongs between two bf16 buffers.
__global__ __launch_bounds__(1024, 4) void lstm_persistent(
    const float* __restrict__ W_hh, const float* __restrict__ xp,
    unsigned short* __restrict__ h0, unsigned short* __restrict__ h1,
    float* __restrict__ hf32)
{
    __shared__ floatx4 part[16 * 64];   // 16 KB: per-wave D fragments
    __shared__ float gv[4][4][16];      // [gate][batch][col]

    const int tid   = threadIdx.x;
    const int lane  = tid & 63;
    const int wv    = tid >> 6;         // 0..15
    const int bid   = blockIdx.x;       // 0..255
    const int rr    = lane & 15;
    const int kg    = lane >> 4;
    const int g     = wv >> 2;          // gate 0..3 (i,f,g,o)
    const int kp    = wv & 3;           // K split 0..3
    const int jbase = bid << 4;
    const int kbase = kp << 10;

    // ---- one-shot load + convert W_hh slice into registers (B-frags) ----
    // B-frag lane layout: col n = rr -> W row (g*4096 + jbase + rr),
    //                     k = kbase + ks*32 + kg*8 + [0..8)
    const float* wrow = W_hh + (size_t)(g * LSTM_H + jbase + rr) * LSTM_H + kbase + (kg << 3);
    bhalf8 wfrag[32];
    #pragma unroll
    for (int ks = 0; ks < 32; ++ks) {
        const float4* wp = (const float4*)(wrow + ks * 32);
        float4 a = wp[0], b = wp[1];
        bhalf8 w;
        w[0] = (short)f2bf(a.x); w[1] = (short)f2bf(a.y);
        w[2] = (short)f2bf(a.z); w[3] = (short)f2bf(a.w);
        w[4] = (short)f2bf(b.x); w[5] = (short)f2bf(b.y);
        w[6] = (short)f2bf(b.z); w[7] = (short)f2bf(b.w);
        wfrag[ks] = w;
    }

    // zero h(t=0): each block zeros its 64-ushort slice (256*64 = 16384)
    if (tid < 64) h0[(bid << 6) + tid] = 0;

    float creg = 0.0f;  // c state: wave0 lane -> (batch=lane>>4, col=lane&15)

    cg::grid_group grid = cg::this_grid();
    grid.sync();

    // A-frag address: row m = rr (batch; rows 4..15 duplicate rows 0..3 and
    // produce D rows we never read), k = kbase + ks*32 + kg*8
    const int arow = (rr & 3) * LSTM_H + kbase + (kg << 3);

    for (int t = 0; t < T_STEPS; ++t) {
        const unsigned short* hc = (t & 1) ? h1 : h0;
        unsigned short* hn       = (t & 1) ? h0 : h1;

        // prefetch xp for this step (wave 0 only) to overlap with MFMA phase
        float xpv0 = 0.f, xpv1 = 0.f, xpv2 = 0.f, xpv3 = 0.f;
        size_t xb = 0;
        if (wv == 0) {
            xb = ((size_t)(kg * T_STEPS + t)) * GATES + jbase + rr;
            xpv0 = xp[xb];
            xpv1 = xp[xb + LSTM_H];
            xpv2 = xp[xb + 2 * LSTM_H];
            xpv3 = xp[xb + 3 * LSTM_H];
        }

        floatx4 acc = (floatx4){0.f, 0.f, 0.f, 0.f};
        #pragma unroll
        for (int ks = 0; ks < 32; ++ks) {
            bhalf8 af = *(const bhalf8*)(hc + arow + ks * 32);
            acc = __builtin_amdgcn_mfma_f32_16x16x32_bf16(af, wfrag[ks], acc, 0, 0, 0);
        }
        part[wv * 64 + lane] = acc;
        __syncthreads();

        if (wv < 4) {  // wave wv reduces split-K for gate wv
            floatx4 r0 = part[(wv * 4 + 0) * 64 + lane];
            floatx4 r1 = part[(wv * 4 + 1) * 64 + lane];
            floatx4 r2 = part[(wv * 4 + 2) * 64 + lane];
            floatx4 r3 = part[(wv * 4 + 3) * 64 + lane];
            floatx4 r = (r0 + r1) + (r2 + r3);
            // D mapping: col = lane&15, row = (lane>>4)*4 + i; rows 0..3 = batches
            if (kg == 0) {
                #pragma unroll
                for (int i = 0; i < 4; ++i) gv[wv][i][rr] = r[i];
            }
        }
        __syncthreads();

        if (wv == 0) {
            const int batch = kg;   // 0..3
            const int col   = rr;   // 0..15
            float gi = sigmoidf_(gv[0][batch][col] + xpv0);
            float gf = sigmoidf_(gv[1][batch][col] + xpv1);
            float gg = tanhf   (gv[2][batch][col] + xpv2);
            float go = sigmoidf_(gv[3][batch][col] + xpv3);
            float cn = gf * creg + gi * gg;
            float hv = go * tanhf(cn);
            creg = cn;
            hn[batch * LSTM_H + jbase + col] = f2bf(hv);
            if (t == T_STEPS - 1) hf32[batch * LSTM_H + jbase + col] = hv;
        }
        __threadfence();
        grid.sync();
    }
}

// -------------------------------------------------- final FC
__global__ void final_fc(const float* __restrict__ h, const float* __restrict__ fcW,
                         const float* __restrict__ fcb, float* __restrict__ out)
{
    int i = threadIdx.x;
    if (i < 128) {
        int b = i >> 5, n = i & 31;
        const float* hp = h + (size_t)b * LSTM_H + n * 128;
        float s = 0.0f;
        #pragma unroll 8
        for (int l = 0; l < 128; ++l) s += hp[l] * fcW[l];
        out[i] = s + fcb[0];
    }
}

extern "C" void kernel_launch(void* const* d_in, const int* in_sizes, int n_in,
                              void* d_out, int out_size, void* d_ws, size_t ws_size,
                              hipStream_t stream)
{
    const float* x    = (const float*)d_in[0];
    const int*   ei   = (const int*)d_in[1];
    const float* ln_g = (const float*)d_in[2];
    const float* ln_b = (const float*)d_in[3];
    const float* W1   = (const float*)d_in[4];
    const float* b1   = (const float*)d_in[5];
    const float* W2   = (const float*)d_in[6];
    const float* b2   = (const float*)d_in[7];
    const float* W_ih = (const float*)d_in[8];
    const float* b_ih = (const float*)d_in[9];
    const float* W_hh = (const float*)d_in[10];
    const float* b_hh = (const float*)d_in[11];
    const float* fcW  = (const float*)d_in[12];
    const float* fcb  = (const float*)d_in[13];
    int E = in_sizes[1] / 2;

    float* ws    = (float*)d_ws;
    float* A     = ws;                         // 1024
    float* seq   = A + 1024;                   // 262144
    float* xp    = seq + 262144;               // 2097152
    float* xpart = xp + 2097152;               // 8388608
    float* hf32  = xpart + 8388608;            // 16384
    unsigned short* hb0 = (unsigned short*)(hf32 + 16384);   // 16384 ushort
    unsigned short* hb1 = (unsigned short*)(hf32 + 16384 + 8192);
    // total ~43 MB

    build_adj<<<dim3(1), dim3(256), 0, stream>>>(ei, E, A);
    gcn2_kernel<<<dim3(BT), dim3(256), 0, stream>>>(x, ln_g, ln_b, W1, b1, W2, b2, A, seq);
    xproj_mfma<<<dim3(1024), dim3(256), 0, stream>>>(seq, W_ih, xpart);
    combine_xp<<<dim3(2048), dim3(256), 0, stream>>>(xpart, b_ih, b_hh, xp);

    void* kargs[5];
    kargs[0] = (void*)&W_hh;
    kargs[1] = (void*)&xp;
    kargs[2] = (void*)&hb0;
    kargs[3] = (void*)&hb1;
    kargs[4] = (void*)&hf32;
    hipLaunchCooperativeKernel(lstm_persistent, dim3(256), dim3(1024), kargs, 0, stream);

    final_fc<<<dim3(1), dim3(128), 0, stream>>>(hf32, fcW, fcb, (float*)d_out);
}

// Round 2
// 4159.662 us; speedup vs baseline: 1.0135x; 1.0135x over previous
//
#include <hip/hip_runtime.h>
#include <hip/hip_cooperative_groups.h>
#include <math.h>

namespace cg = cooperative_groups;

// B=4, T=32, N=32, F=16, GH=64, LH=128
#define T_STEPS 32
#define NNODES  32
#define FEAT    16
#define GHID    64
#define LSTM_IN 2048   // N*GH
#define LSTM_H  4096   // N*LH
#define GATES   16384  // 4*LSTM_H
#define BT      128    // B*T

typedef __attribute__((ext_vector_type(8))) short bhalf8;
typedef __attribute__((ext_vector_type(4))) float floatx4;

__device__ __forceinline__ float sigmoidf_(float x) { return 1.0f / (1.0f + __expf(-x)); }

// fp32 -> bf16 (RNE)
__device__ __forceinline__ unsigned short f2bf(float f) {
    unsigned int u = __float_as_uint(f);
    u += 0x7FFFu + ((u >> 16) & 1u);
    return (unsigned short)(u >> 16);
}

// ------------------------------------------------- dense normalized adjacency
__global__ void build_adj(const int* __restrict__ ei, int E, float* __restrict__ A) {
    __shared__ float As[NNODES * NNODES];
    __shared__ int   deg[NNODES];
    __shared__ float dinv[NNODES];
    int tid = threadIdx.x;
    if (tid < NNODES) deg[tid] = 1;
    for (int i = tid; i < NNODES * NNODES; i += 256) As[i] = 0.0f;
    __syncthreads();
    for (int e = tid; e < E; e += 256) atomicAdd(&deg[ei[E + e]], 1);
    __syncthreads();
    if (tid < NNODES) dinv[tid] = rsqrtf((float)deg[tid]);
    __syncthreads();
    for (int e = tid; e < E; e += 256) {
        int s = ei[e], d = ei[E + e];
        atomicAdd(&As[d * NNODES + s], dinv[s] * dinv[d]);
    }
    if (tid < NNODES) atomicAdd(&As[tid * NNODES + tid], dinv[tid] * dinv[tid]);
    __syncthreads();
    for (int i = tid; i < NNODES * NNODES; i += 256) A[i] = As[i];
}

// ------------------------------------------- LN + GCN1 + GCN2, one block/(b,t)
__global__ __launch_bounds__(256) void gcn2_kernel(
    const float* __restrict__ x, const float* __restrict__ ln_g, const float* __restrict__ ln_b,
    const float* __restrict__ W1, const float* __restrict__ b1,
    const float* __restrict__ W2, const float* __restrict__ b2,
    const float* __restrict__ A, float* __restrict__ seq)
{
    __shared__ float As[NNODES * NNODES];
    __shared__ float w1[FEAT * GHID];
    __shared__ float w2[GHID * GHID];
    __shared__ float xln[NNODES * FEAT];
    __shared__ float h1[NNODES * GHID];
    __shared__ float g1[NNODES * GHID];
    __shared__ float h2[NNODES * GHID];

    int tid = threadIdx.x;
    int bt = blockIdx.x;
    const float* xb = x + (size_t)bt * NNODES * FEAT;

    for (int i = tid; i < 1024; i += 256) As[i] = A[i];
    for (int i = tid; i < FEAT * GHID; i += 256) w1[i] = W1[i];
    for (int i = tid; i < GHID * GHID; i += 256) w2[i] = W2[i];
    for (int i = tid; i < NNODES * FEAT; i += 256) xln[i] = xb[i];
    __syncthreads();

    if (tid < NNODES) {
        float mu = 0.0f;
        for (int f = 0; f < FEAT; ++f) mu += xln[tid * FEAT + f];
        mu *= (1.0f / FEAT);
        float var = 0.0f;
        for (int f = 0; f < FEAT; ++f) { float d = xln[tid * FEAT + f] - mu; var += d * d; }
        var *= (1.0f / FEAT);
        float r = rsqrtf(var + 1e-5f);
        for (int f = 0; f < FEAT; ++f)
            xln[tid * FEAT + f] = (xln[tid * FEAT + f] - mu) * r * ln_g[f] + ln_b[f];
    }
    __syncthreads();

    for (int idx = tid; idx < NNODES * GHID; idx += 256) {
        int n = idx >> 6, j = idx & 63;
        float s = 0.0f;
        #pragma unroll
        for (int f = 0; f < FEAT; ++f) s += xln[n * FEAT + f] * w1[f * GHID + j];
        h1[idx] = s;
    }
    __syncthreads();
    for (int idx = tid; idx < NNODES * GHID; idx += 256) {
        int n = idx >> 6, j = idx & 63;
        float s = b1[j];
        #pragma unroll 8
        for (int m = 0; m < NNODES; ++m) s += As[n * NNODES + m] * h1[m * GHID + j];
        g1[idx] = s;
    }
    __syncthreads();
    for (int idx = tid; idx < NNODES * GHID; idx += 256) {
        int n = idx >> 6, j = idx & 63;
        float s = 0.0f;
        #pragma unroll 8
        for (int k = 0; k < GHID; ++k) s += g1[n * GHID + k] * w2[k * GHID + j];
        h2[idx] = s;
    }
    __syncthreads();
    for (int idx = tid; idx < NNODES * GHID; idx += 256) {
        int n = idx >> 6, j = idx & 63;
        float s = b2[j];
        #pragma unroll 8
        for (int m = 0; m < NNODES; ++m) s += As[n * NNODES + m] * h2[m * GHID + j];
        seq[(size_t)bt * LSTM_IN + idx] = s;
    }
}

// ---------------------------------- x_proj partials via MFMA, fused fp32->bf16
__global__ __launch_bounds__(256) void xproj_mfma(
    const float* __restrict__ seq, const float* __restrict__ W_ih,
    float* __restrict__ xpart)
{
    int lane = threadIdx.x & 63;
    int wid = blockIdx.x * 4 + (threadIdx.x >> 6);  // 0..4095
    int ntile = wid >> 2;                            // 0..1023
    int kc = wid & 3;                                // 0..3
    int n0 = ntile << 4;
    int rr = lane & 15;
    int kg = lane >> 4;

    floatx4 acc[8];
    #pragma unroll
    for (int mt = 0; mt < 8; ++mt) acc[mt] = (floatx4){0.f, 0.f, 0.f, 0.f};

    for (int ks = 0; ks < 16; ++ks) {
        int k0 = (kc << 9) + (ks << 5) + (kg << 3);
        const float4* wp = (const float4*)(W_ih + (size_t)(n0 + rr) * LSTM_IN + k0);
        float4 w0 = wp[0], w1 = wp[1];
        bhalf8 bf;
        bf[0] = (short)f2bf(w0.x); bf[1] = (short)f2bf(w0.y);
        bf[2] = (short)f2bf(w0.z); bf[3] = (short)f2bf(w0.w);
        bf[4] = (short)f2bf(w1.x); bf[5] = (short)f2bf(w1.y);
        bf[6] = (short)f2bf(w1.z); bf[7] = (short)f2bf(w1.w);
        #pragma unroll
        for (int mt = 0; mt < 8; ++mt) {
            const float4* ap = (const float4*)(seq + (size_t)(mt * 16 + rr) * LSTM_IN + k0);
            float4 a0 = ap[0], a1 = ap[1];
            bhalf8 af;
            af[0] = (short)f2bf(a0.x); af[1] = (short)f2bf(a0.y);
            af[2] = (short)f2bf(a0.z); af[3] = (short)f2bf(a0.w);
            af[4] = (short)f2bf(a1.x); af[5] = (short)f2bf(a1.y);
            af[6] = (short)f2bf(a1.z); af[7] = (short)f2bf(a1.w);
            acc[mt] = __builtin_amdgcn_mfma_f32_16x16x32_bf16(af, bf, acc[mt], 0, 0, 0);
        }
    }
    float* xo = xpart + (size_t)kc * (BT * GATES);
    #pragma unroll
    for (int mt = 0; mt < 8; ++mt) {
        #pragma unroll
        for (int i = 0; i < 4; ++i) {
            int row = mt * 16 + kg * 4 + i;
            xo[(size_t)row * GATES + n0 + rr] = acc[mt][i];
        }
    }
}

// -------------------------------- combine 4 K-partials + bias -> xp
__global__ void combine_xp(const float* __restrict__ xpart,
                           const float* __restrict__ b_ih, const float* __restrict__ b_hh,
                           float* __restrict__ xp)
{
    int i = blockIdx.x * 256 + threadIdx.x;
    const float4* p0 = (const float4*)xpart;
    const float4* p1 = p0 + (BT * GATES / 4);
    const float4* p2 = p1 + (BT * GATES / 4);
    const float4* p3 = p2 + (BT * GATES / 4);
    float4 a = p0[i], b = p1[i], c = p2[i], d = p3[i];
    int col = (i & (GATES / 4 - 1)) << 2;
    float4 o;
    o.x = a.x + b.x + c.x + d.x + b_ih[col + 0] + b_hh[col + 0];
    o.y = a.y + b.y + c.y + d.y + b_ih[col + 1] + b_hh[col + 1];
    o.z = a.z + b.z + c.z + d.z + b_ih[col + 2] + b_hh[col + 2];
    o.w = a.w + b.w + c.w + d.w + b_ih[col + 3] + b_hh[col + 3];
    ((float4*)xp)[i] = o;
}

// -------------------- W_hh fp32 -> bf16, rewritten in MFMA-B-fragment order
// Fragment-order linear index t (one per 8-elem chunk):
//   lane = t&63, ks = (t>>6)&31, wv = (t>>11)&15, bid = t>>15
//   rr = lane&15, kg = lane>>4, g = wv>>2, kp = wv&3
//   value = W_hh[g*4096 + bid*16 + rr][kp*1024 + ks*32 + kg*8 + 0..8)
// So the persistent kernel's per-wave weight stream is 32 KB CONTIGUOUS.
__global__ __launch_bounds__(256) void conv_whh_frag(
    const float* __restrict__ W, unsigned short* __restrict__ Wf)
{
    int t = blockIdx.x * 256 + threadIdx.x;   // 0 .. 8388607
    int lane = t & 63;
    int ks   = (t >> 6) & 31;
    int wv   = (t >> 11) & 15;
    int bid  = t >> 15;
    int rr = lane & 15, kg = lane >> 4;
    int g = wv >> 2, kp = wv & 3;
    const float* s = W + ((size_t)(g * LSTM_H + (bid << 4) + rr) << 12)
                       + (kp << 10) + (ks << 5) + (kg << 3);
    float4 a = ((const float4*)s)[0];
    float4 b = ((const float4*)s)[1];
    bhalf8 w;
    w[0] = (short)f2bf(a.x); w[1] = (short)f2bf(a.y);
    w[2] = (short)f2bf(a.z); w[3] = (short)f2bf(a.w);
    w[4] = (short)f2bf(b.x); w[5] = (short)f2bf(b.y);
    w[6] = (short)f2bf(b.z); w[7] = (short)f2bf(b.w);
    *(bhalf8*)(Wf + (size_t)t * 8) = w;
}

// -------------------------------------------------- persistent LSTM recurrence
// 256 blocks x 1024 threads (1 block/CU, 4 waves/SIMD, <=128 VGPR).
// Weights are STREAMED from L3 each step (fragment-ordered bf16 Wbf), not
// register-pinned (the full W_hh equals the chip's entire 128 MB VGPR file —
// round-1's spill disaster). Block b owns j in [16b,16b+16) for all 4 gates;
// wave w: gate=w>>2, Ksplit=w&3 (K range 1024 -> 32 MFMAs/step, 32 KB weight
// stream/wave/step, contiguous). Per step: MFMA partials -> LDS split-K reduce
// -> wave0 computes gates/c/h (c in wave0 registers) -> one grid.sync().
__global__ __launch_bounds__(1024, 4) void lstm_persistent(
    const unsigned short* __restrict__ Wbf, const float* __restrict__ xp,
    unsigned short* __restrict__ h0, unsigned short* __restrict__ h1,
    float* __restrict__ hf32)
{
    __shared__ floatx4 part[16 * 64];   // 16 KB: per-wave D fragments
    __shared__ float gv[4][4][16];      // [gate][batch][col]

    const int tid   = threadIdx.x;
    const int lane  = tid & 63;
    const int wv    = tid >> 6;         // 0..15
    const int bid   = blockIdx.x;       // 0..255
    const int rr    = lane & 15;
    const int kg    = lane >> 4;
    const int kp    = wv & 3;           // K split 0..3
    const int jbase = bid << 4;
    const int kbase = kp << 10;

    // wave's contiguous weight slice: 32 frags x 512 ushorts
    const unsigned short* wbase = Wbf + (((size_t)(bid * 16 + wv)) << 14) + (lane << 3);

    // zero h(t=0): each block zeros its 64-ushort slice (256*64 = 16384)
    if (tid < 64) h0[(bid << 6) + tid] = 0;

    float creg = 0.0f;  // c state: wave0 lane -> (batch=lane>>4, col=lane&15)

    cg::grid_group grid = cg::this_grid();
    grid.sync();

    // A-frag: row m = batch (rows 4..15 duplicate 0..3; D rows we never read),
    // k = kbase + ks*32 + kg*8
    const int arow = (rr & 3) * LSTM_H + kbase + (kg << 3);

    for (int t = 0; t < T_STEPS; ++t) {
        const unsigned short* hc = (t & 1) ? h1 : h0;
        unsigned short* hn       = (t & 1) ? h0 : h1;

        // prefetch xp for this step (wave 0 only) to overlap with MFMA phase
        float xpv0 = 0.f, xpv1 = 0.f, xpv2 = 0.f, xpv3 = 0.f;
        if (wv == 0) {
            size_t xb = ((size_t)(kg * T_STEPS + t)) * GATES + jbase + rr;
            xpv0 = xp[xb];
            xpv1 = xp[xb + LSTM_H];
            xpv2 = xp[xb + 2 * LSTM_H];
            xpv3 = xp[xb + 3 * LSTM_H];
        }

        floatx4 acc = (floatx4){0.f, 0.f, 0.f, 0.f};
        #pragma unroll
        for (int ks = 0; ks < 32; ++ks) {
            bhalf8 wf = *(const bhalf8*)(wbase + (ks << 9));
            bhalf8 af = *(const bhalf8*)(hc + arow + (ks << 5));
            acc = __builtin_amdgcn_mfma_f32_16x16x32_bf16(af, wf, acc, 0, 0, 0);
        }
        part[wv * 64 + lane] = acc;
        __syncthreads();

        if (wv < 4) {  // wave wv reduces split-K for gate wv
            floatx4 r0 = part[(wv * 4 + 0) * 64 + lane];
            floatx4 r1 = part[(wv * 4 + 1) * 64 + lane];
            floatx4 r2 = part[(wv * 4 + 2) * 64 + lane];
            floatx4 r3 = part[(wv * 4 + 3) * 64 + lane];
            floatx4 r = (r0 + r1) + (r2 + r3);
            // D mapping: col = lane&15, row = (lane>>4)*4 + i; rows 0..3 = batches
            if (kg == 0) {
                #pragma unroll
                for (int i = 0; i < 4; ++i) gv[wv][i][rr] = r[i];
            }
        }
        __syncthreads();

        if (wv == 0) {
            const int batch = kg;   // 0..3
            const int col   = rr;   // 0..15
            float gi = sigmoidf_(gv[0][batch][col] + xpv0);
            float gf = sigmoidf_(gv[1][batch][col] + xpv1);
            float gg = tanhf   (gv[2][batch][col] + xpv2);
            float go = sigmoidf_(gv[3][batch][col] + xpv3);
            float cn = gf * creg + gi * gg;
            float hv = go * tanhf(cn);
            creg = cn;
            hn[batch * LSTM_H + jbase + col] = f2bf(hv);
            if (t == T_STEPS - 1) hf32[batch * LSTM_H + jbase + col] = hv;
        }
        __threadfence();
        grid.sync();
    }
}

// -------------------------------------------------- final FC
__global__ void final_fc(const float* __restrict__ h, const float* __restrict__ fcW,
                         const float* __restrict__ fcb, float* __restrict__ out)
{
    int i = threadIdx.x;
    if (i < 128) {
        int b = i >> 5, n = i & 31;
        const float* hp = h + (size_t)b * LSTM_H + n * 128;
        float s = 0.0f;
        #pragma unroll 8
        for (int l = 0; l < 128; ++l) s += hp[l] * fcW[l];
        out[i] = s + fcb[0];
    }
}

extern "C" void kernel_launch(void* const* d_in, const int* in_sizes, int n_in,
                              void* d_out, int out_size, void* d_ws, size_t ws_size,
                              hipStream_t stream)
{
    const float* x    = (const float*)d_in[0];
    const int*   ei   = (const int*)d_in[1];
    const float* ln_g = (const float*)d_in[2];
    const float* ln_b = (const float*)d_in[3];
    const float* W1   = (const float*)d_in[4];
    const float* b1   = (const float*)d_in[5];
    const float* W2   = (const float*)d_in[6];
    const float* b2   = (const float*)d_in[7];
    const float* W_ih = (const float*)d_in[8];
    const float* b_ih = (const float*)d_in[9];
    const float* W_hh = (const float*)d_in[10];
    const float* b_hh = (const float*)d_in[11];
    const float* fcW  = (const float*)d_in[12];
    const float* fcb  = (const float*)d_in[13];
    int E = in_sizes[1] / 2;

    float* ws    = (float*)d_ws;
    float* A     = ws;                         // 1024
    float* seq   = A + 1024;                   // 262144
    float* xp    = seq + 262144;               // 2097152
    float* xpart = xp + 2097152;               // 8388608
    float* hf32  = xpart + 8388608;            // 16384
    unsigned short* hb0 = (unsigned short*)(hf32 + 16384);       // 16384 ushort
    unsigned short* hb1 = (unsigned short*)(hf32 + 16384 + 8192);
    unsigned short* Wbf = (unsigned short*)(hf32 + 16384 + 16384); // 64M ushort (128 MB)
    // total ~171 MB

    build_adj<<<dim3(1), dim3(256), 0, stream>>>(ei, E, A);
    gcn2_kernel<<<dim3(BT), dim3(256), 0, stream>>>(x, ln_g, ln_b, W1, b1, W2, b2, A, seq);
    xproj_mfma<<<dim3(1024), dim3(256), 0, stream>>>(seq, W_ih, xpart);
    combine_xp<<<dim3(2048), dim3(256), 0, stream>>>(xpart, b_ih, b_hh, xp);
    conv_whh_frag<<<dim3(32768), dim3(256), 0, stream>>>(W_hh, Wbf);

    void* kargs[5];
    kargs[0] = (void*)&Wbf;
    kargs[1] = (void*)&xp;
    kargs[2] = (void*)&hb0;
    kargs[3] = (void*)&hb1;
    kargs[4] = (void*)&hf32;
    hipLaunchCooperativeKernel(lstm_persistent, dim3(256), dim3(1024), kargs, 0, stream);

    final_fc<<<dim3(1), dim3(128), 0, stream>>>(hf32, fcW, fcb, (float*)d_out);
}

// Round 5
// 3956.915 us; speedup vs baseline: 1.0654x; 1.0512x over previous
//
#include <hip/hip_runtime.h>
#include <hip/hip_cooperative_groups.h>
#include <math.h>

namespace cg = cooperative_groups;

// B=4, T=32, N=32, F=16, GH=64, LH=128
#define T_STEPS 32
#define NNODES  32
#define FEAT    16
#define GHID    64
#define LSTM_IN 2048   // N*GH
#define LSTM_H  4096   // N*LH
#define GATES   16384  // 4*LSTM_H
#define BT      128    // B*T

typedef __attribute__((ext_vector_type(8))) short bhalf8;
typedef __attribute__((ext_vector_type(4))) float floatx4;

__device__ __forceinline__ float sigmoidf_(float x) { return 1.0f / (1.0f + __expf(-x)); }

// fp32 -> bf16 (RNE)
__device__ __forceinline__ unsigned short f2bf(float f) {
    unsigned int u = __float_as_uint(f);
    u += 0x7FFFu + ((u >> 16) & 1u);
    return (unsigned short)(u >> 16);
}

// ------------------------------------------------- dense normalized adjacency
__global__ void build_adj(const int* __restrict__ ei, int E, float* __restrict__ A) {
    __shared__ float As[NNODES * NNODES];
    __shared__ int   deg[NNODES];
    __shared__ float dinv[NNODES];
    int tid = threadIdx.x;
    if (tid < NNODES) deg[tid] = 1;
    for (int i = tid; i < NNODES * NNODES; i += 256) As[i] = 0.0f;
    __syncthreads();
    for (int e = tid; e < E; e += 256) atomicAdd(&deg[ei[E + e]], 1);
    __syncthreads();
    if (tid < NNODES) dinv[tid] = rsqrtf((float)deg[tid]);
    __syncthreads();
    for (int e = tid; e < E; e += 256) {
        int s = ei[e], d = ei[E + e];
        atomicAdd(&As[d * NNODES + s], dinv[s] * dinv[d]);
    }
    if (tid < NNODES) atomicAdd(&As[tid * NNODES + tid], dinv[tid] * dinv[tid]);
    __syncthreads();
    for (int i = tid; i < NNODES * NNODES; i += 256) A[i] = As[i];
}

// ------------------------------------------- LN + GCN1 + GCN2, one block/(b,t)
__global__ __launch_bounds__(256) void gcn2_kernel(
    const float* __restrict__ x, const float* __restrict__ ln_g, const float* __restrict__ ln_b,
    const float* __restrict__ W1, const float* __restrict__ b1,
    const float* __restrict__ W2, const float* __restrict__ b2,
    const float* __restrict__ A, float* __restrict__ seq)
{
    __shared__ float As[NNODES * NNODES];
    __shared__ float w1[FEAT * GHID];
    __shared__ float w2[GHID * GHID];
    __shared__ float xln[NNODES * FEAT];
    __shared__ float h1[NNODES * GHID];
    __shared__ float g1[NNODES * GHID];
    __shared__ float h2[NNODES * GHID];

    int tid = threadIdx.x;
    int bt = blockIdx.x;
    const float* xb = x + (size_t)bt * NNODES * FEAT;

    for (int i = tid; i < 1024; i += 256) As[i] = A[i];
    for (int i = tid; i < FEAT * GHID; i += 256) w1[i] = W1[i];
    for (int i = tid; i < GHID * GHID; i += 256) w2[i] = W2[i];
    for (int i = tid; i < NNODES * FEAT; i += 256) xln[i] = xb[i];
    __syncthreads();

    if (tid < NNODES) {
        float mu = 0.0f;
        for (int f = 0; f < FEAT; ++f) mu += xln[tid * FEAT + f];
        mu *= (1.0f / FEAT);
        float var = 0.0f;
        for (int f = 0; f < FEAT; ++f) { float d = xln[tid * FEAT + f] - mu; var += d * d; }
        var *= (1.0f / FEAT);
        float r = rsqrtf(var + 1e-5f);
        for (int f = 0; f < FEAT; ++f)
            xln[tid * FEAT + f] = (xln[tid * FEAT + f] - mu) * r * ln_g[f] + ln_b[f];
    }
    __syncthreads();

    for (int idx = tid; idx < NNODES * GHID; idx += 256) {
        int n = idx >> 6, j = idx & 63;
        float s = 0.0f;
        #pragma unroll
        for (int f = 0; f < FEAT; ++f) s += xln[n * FEAT + f] * w1[f * GHID + j];
        h1[idx] = s;
    }
    __syncthreads();
    for (int idx = tid; idx < NNODES * GHID; idx += 256) {
        int n = idx >> 6, j = idx & 63;
        float s = b1[j];
        #pragma unroll 8
        for (int m = 0; m < NNODES; ++m) s += As[n * NNODES + m] * h1[m * GHID + j];
        g1[idx] = s;
    }
    __syncthreads();
    for (int idx = tid; idx < NNODES * GHID; idx += 256) {
        int n = idx >> 6, j = idx & 63;
        float s = 0.0f;
        #pragma unroll 8
        for (int k = 0; k < GHID; ++k) s += g1[n * GHID + k] * w2[k * GHID + j];
        h2[idx] = s;
    }
    __syncthreads();
    for (int idx = tid; idx < NNODES * GHID; idx += 256) {
        int n = idx >> 6, j = idx & 63;
        float s = b2[j];
        #pragma unroll 8
        for (int m = 0; m < NNODES; ++m) s += As[n * NNODES + m] * h2[m * GHID + j];
        seq[(size_t)bt * LSTM_IN + idx] = s;
    }
}

// ---------------------------------- x_proj partials via MFMA, fused fp32->bf16
__global__ __launch_bounds__(256) void xproj_mfma(
    const float* __restrict__ seq, const float* __restrict__ W_ih,
    float* __restrict__ xpart)
{
    int lane = threadIdx.x & 63;
    int wid = blockIdx.x * 4 + (threadIdx.x >> 6);  // 0..4095
    int ntile = wid >> 2;                            // 0..1023
    int kc = wid & 3;                                // 0..3
    int n0 = ntile << 4;
    int rr = lane & 15;
    int kg = lane >> 4;

    floatx4 acc[8];
    #pragma unroll
    for (int mt = 0; mt < 8; ++mt) acc[mt] = (floatx4){0.f, 0.f, 0.f, 0.f};

    for (int ks = 0; ks < 16; ++ks) {
        int k0 = (kc << 9) + (ks << 5) + (kg << 3);
        const float4* wp = (const float4*)(W_ih + (size_t)(n0 + rr) * LSTM_IN + k0);
        float4 w0 = wp[0], w1 = wp[1];
        bhalf8 bf;
        bf[0] = (short)f2bf(w0.x); bf[1] = (short)f2bf(w0.y);
        bf[2] = (short)f2bf(w0.z); bf[3] = (short)f2bf(w0.w);
        bf[4] = (short)f2bf(w1.x); bf[5] = (short)f2bf(w1.y);
        bf[6] = (short)f2bf(w1.z); bf[7] = (short)f2bf(w1.w);
        #pragma unroll
        for (int mt = 0; mt < 8; ++mt) {
            const float4* ap = (const float4*)(seq + (size_t)(mt * 16 + rr) * LSTM_IN + k0);
            float4 a0 = ap[0], a1 = ap[1];
            bhalf8 af;
            af[0] = (short)f2bf(a0.x); af[1] = (short)f2bf(a0.y);
            af[2] = (short)f2bf(a0.z); af[3] = (short)f2bf(a0.w);
            af[4] = (short)f2bf(a1.x); af[5] = (short)f2bf(a1.y);
            af[6] = (short)f2bf(a1.z); af[7] = (short)f2bf(a1.w);
            acc[mt] = __builtin_amdgcn_mfma_f32_16x16x32_bf16(af, bf, acc[mt], 0, 0, 0);
        }
    }
    float* xo = xpart + (size_t)kc * (BT * GATES);
    #pragma unroll
    for (int mt = 0; mt < 8; ++mt) {
        #pragma unroll
        for (int i = 0; i < 4; ++i) {
            int row = mt * 16 + kg * 4 + i;
            xo[(size_t)row * GATES + n0 + rr] = acc[mt][i];
        }
    }
}

// -------------------------------- combine 4 K-partials + bias -> xp
__global__ void combine_xp(const float* __restrict__ xpart,
                           const float* __restrict__ b_ih, const float* __restrict__ b_hh,
                           float* __restrict__ xp)
{
    int i = blockIdx.x * 256 + threadIdx.x;
    const float4* p0 = (const float4*)xpart;
    const float4* p1 = p0 + (BT * GATES / 4);
    const float4* p2 = p1 + (BT * GATES / 4);
    const float4* p3 = p2 + (BT * GATES / 4);
    float4 a = p0[i], b = p1[i], c = p2[i], d = p3[i];
    int col = (i & (GATES / 4 - 1)) << 2;
    float4 o;
    o.x = a.x + b.x + c.x + d.x + b_ih[col + 0] + b_hh[col + 0];
    o.y = a.y + b.y + c.y + d.y + b_ih[col + 1] + b_hh[col + 1];
    o.z = a.z + b.z + c.z + d.z + b_ih[col + 2] + b_hh[col + 2];
    o.w = a.w + b.w + c.w + d.w + b_ih[col + 3] + b_hh[col + 3];
    ((float4*)xp)[i] = o;
}

// -------------------- W_hh fp32 -> bf16, rewritten in MFMA-B-fragment order
// Layout for the 8-wave persistent kernel. Per 8-elem chunk index t:
//   lane = t&63, ks = (t>>6)&63, wv = (t>>12)&7, bid = t>>15
//   rr = lane&15, kg = lane>>4, g = wv>>1, kh = wv&1
//   value = W_hh[g*4096 + bid*16 + rr][kh*2048 + ks*32 + kg*8 + 0..8)
// So wave (bid,wv)'s per-step weight stream is 64 KB CONTIGUOUS (64 frags x 1KB).
__global__ __launch_bounds__(256) void conv_whh_frag(
    const float* __restrict__ W, unsigned short* __restrict__ Wf)
{
    int t = blockIdx.x * 256 + threadIdx.x;   // 0 .. 8388607
    int lane = t & 63;
    int ks   = (t >> 6) & 63;
    int wv   = (t >> 12) & 7;
    int bid  = t >> 15;
    int rr = lane & 15, kg = lane >> 4;
    int g = wv >> 1, kh = wv & 1;
    const float* s = W + ((size_t)(g * LSTM_H + (bid << 4) + rr) << 12)
                       + (kh << 11) + (ks << 5) + (kg << 3);
    float4 a = ((const float4*)s)[0];
    float4 b = ((const float4*)s)[1];
    bhalf8 w;
    w[0] = (short)f2bf(a.x); w[1] = (short)f2bf(a.y);
    w[2] = (short)f2bf(a.z); w[3] = (short)f2bf(a.w);
    w[4] = (short)f2bf(b.x); w[5] = (short)f2bf(b.y);
    w[6] = (short)f2bf(b.z); w[7] = (short)f2bf(b.w);
    *(bhalf8*)(Wf + (size_t)t * 8) = w;
}

// -------------------------------------------------- persistent LSTM recurrence
// 256 blocks x 512 threads (8 waves, 2 waves/EU, <=256 VGPR). Round-2 showed
// the weight stream latency-bound at 1.16 TB/s (64-VGPR wave -> ~12 loads in
// flight). Fix HERE: register double-buffered weight stream. Each wave owns
// (gate = wv>>1, k-half = wv&1): 64 frags (64 KB)/step, processed as 4 chunks
// of 16; chunk c+1's 16 global_load_dwordx4 are issued BEFORE consuming chunk
// c (sched_barrier(0) pins phase order), so 16-32 KB/wave stays in flight and
// the stream is L3-supply-bound. NO manual vmcnt, NO global_load_lds, NO big
// LDS ring (rounds 3-4's suspects) — all waits are compiler-inserted.
// Sync: cg::grid.sync + threadfence + plain h stores/loads (proven rounds 1-2).
// h is staged to LDS per block so the hot loop reads A-frags via ds_read.
__global__ __launch_bounds__(512, 2) void lstm_persistent(
    const unsigned short* __restrict__ Wbf, const float* __restrict__ xp,
    unsigned short* __restrict__ h0, unsigned short* __restrict__ h1,
    float* __restrict__ hf32)
{
    __shared__ __align__(16) unsigned short hlds[4 * LSTM_H];  // 32 KB
    __shared__ floatx4 part[8 * 64];                           // 8 KB
    __shared__ float gv[4][4][16];                             // 1 KB

    const int tid   = threadIdx.x;
    const int lane  = tid & 63;
    const int wv    = tid >> 6;         // 0..7
    const int bid   = blockIdx.x;       // 0..255
    const int rr    = lane & 15;
    const int kg    = lane >> 4;
    const int kh    = wv & 1;           // k half 0..1
    const int jbase = bid << 4;

    // wave's contiguous 64 KB weight slice (64 frags x 512 ushorts)
    const unsigned short* wg = Wbf + (((size_t)(bid * 8 + wv)) << 15) + (lane << 3);

    // A-frag LDS byte offset: batch*8192 + kh*4096 + kg*16 (+ ks*64)
    const int abyte = ((rr & 3) << 13) + (kh << 12) + (kg << 4);

    float creg = 0.0f;  // c state: wave0 lane -> (batch=kg, col=rr)

    cg::grid_group grid = cg::this_grid();

    for (int t = 0; t < T_STEPS; ++t) {
        const unsigned short* hc = (t & 1) ? h1 : h0;
        unsigned short* hn       = (t & 1) ? h0 : h1;

        // prefetch xp for this step (wave 0 only); consumed in the epilogue
        float xpv0 = 0.f, xpv1 = 0.f, xpv2 = 0.f, xpv3 = 0.f;
        if (wv == 0) {
            size_t xb = ((size_t)(kg * T_STEPS + t)) * GATES + jbase + rr;
            xpv0 = xp[xb];
            xpv1 = xp[xb + LSTM_H];
            xpv2 = xp[xb + 2 * LSTM_H];
            xpv3 = xp[xb + 3 * LSTM_H];
        }

        floatx4 acc = (floatx4){0.f, 0.f, 0.f, 0.f};
        if (t > 0) {
            // ---- stage full h (32 KB) into LDS; each thread copies 64 B
            {
                const uint4* hsrc = (const uint4*)hc + tid * 4;
                uint4 v0 = hsrc[0], v1 = hsrc[1], v2 = hsrc[2], v3 = hsrc[3];
                uint4* hl = (uint4*)hlds + tid * 4;
                hl[0] = v0; hl[1] = v1; hl[2] = v2; hl[3] = v3;
            }
            __syncthreads();

            // ---- register double-buffered weight stream: 4 chunks x 16 frags
            bhalf8 bA[16], bB[16];
            #pragma unroll
            for (int i = 0; i < 16; ++i)
                bA[i] = *(const bhalf8*)(wg + ((0 * 16 + i) << 9));   // chunk 0
            __builtin_amdgcn_sched_barrier(0);
            #pragma unroll
            for (int i = 0; i < 16; ++i)
                bB[i] = *(const bhalf8*)(wg + ((1 * 16 + i) << 9));   // chunk 1
            __builtin_amdgcn_sched_barrier(0);
            #pragma unroll
            for (int i = 0; i < 16; ++i) {                            // consume 0
                bhalf8 af = *(const bhalf8*)((const char*)hlds + abyte + ((0 * 16 + i) << 6));
                acc = __builtin_amdgcn_mfma_f32_16x16x32_bf16(af, bA[i], acc, 0, 0, 0);
            }
            __builtin_amdgcn_sched_barrier(0);
            #pragma unroll
            for (int i = 0; i < 16; ++i)
                bA[i] = *(const bhalf8*)(wg + ((2 * 16 + i) << 9));   // chunk 2
            __builtin_amdgcn_sched_barrier(0);
            #pragma unroll
            for (int i = 0; i < 16; ++i) {                            // consume 1
                bhalf8 af = *(const bhalf8*)((const char*)hlds + abyte + ((1 * 16 + i) << 6));
                acc = __builtin_amdgcn_mfma_f32_16x16x32_bf16(af, bB[i], acc, 0, 0, 0);
            }
            __builtin_amdgcn_sched_barrier(0);
            #pragma unroll
            for (int i = 0; i < 16; ++i)
                bB[i] = *(const bhalf8*)(wg + ((3 * 16 + i) << 9));   // chunk 3
            __builtin_amdgcn_sched_barrier(0);
            #pragma unroll
            for (int i = 0; i < 16; ++i) {                            // consume 2
                bhalf8 af = *(const bhalf8*)((const char*)hlds + abyte + ((2 * 16 + i) << 6));
                acc = __builtin_amdgcn_mfma_f32_16x16x32_bf16(af, bA[i], acc, 0, 0, 0);
            }
            __builtin_amdgcn_sched_barrier(0);
            #pragma unroll
            for (int i = 0; i < 16; ++i) {                            // consume 3
                bhalf8 af = *(const bhalf8*)((const char*)hlds + abyte + ((3 * 16 + i) << 6));
                acc = __builtin_amdgcn_mfma_f32_16x16x32_bf16(af, bB[i], acc, 0, 0, 0);
            }
        }

        part[(wv << 6) + lane] = acc;
        __syncthreads();

        if (wv < 4) {  // wave wv reduces the 2 k-half partials for gate wv
            floatx4 r = part[((wv * 2 + 0) << 6) + lane] + part[((wv * 2 + 1) << 6) + lane];
            // D mapping: col = lane&15, row = (lane>>4)*4 + i; rows 0..3 = batches
            if (kg == 0) {
                #pragma unroll
                for (int i = 0; i < 4; ++i) gv[wv][i][rr] = r[i];
            }
        }
        __syncthreads();

        if (wv == 0) {
            const int batch = kg;   // 0..3
            const int col   = rr;   // 0..15
            float gi = sigmoidf_(gv[0][batch][col] + xpv0);
            float gf = sigmoidf_(gv[1][batch][col] + xpv1);
            float gg = tanhf   (gv[2][batch][col] + xpv2);
            float go = sigmoidf_(gv[3][batch][col] + xpv3);
            float cn = gf * creg + gi * gg;
            float hval = go * tanhf(cn);
            creg = cn;
            hn[batch * LSTM_H + jbase + col] = f2bf(hval);
            if (t == T_STEPS - 1) hf32[batch * LSTM_H + jbase + col] = hval;
        }
        __threadfence();
        grid.sync();
    }
}

// -------------------------------------------------- final FC
__global__ void final_fc(const float* __restrict__ h, const float* __restrict__ fcW,
                         const float* __restrict__ fcb, float* __restrict__ out)
{
    int i = threadIdx.x;
    if (i < 128) {
        int b = i >> 5, n = i & 31;
        const float* hp = h + (size_t)b * LSTM_H + n * 128;
        float s = 0.0f;
        #pragma unroll 8
        for (int l = 0; l < 128; ++l) s += hp[l] * fcW[l];
        out[i] = s + fcb[0];
    }
}

extern "C" void kernel_launch(void* const* d_in, const int* in_sizes, int n_in,
                              void* d_out, int out_size, void* d_ws, size_t ws_size,
                              hipStream_t stream)
{
    const float* x    = (const float*)d_in[0];
    const int*   ei   = (const int*)d_in[1];
    const float* ln_g = (const float*)d_in[2];
    const float* ln_b = (const float*)d_in[3];
    const float* W1   = (const float*)d_in[4];
    const float* b1   = (const float*)d_in[5];
    const float* W2   = (const float*)d_in[6];
    const float* b2   = (const float*)d_in[7];
    const float* W_ih = (const float*)d_in[8];
    const float* b_ih = (const float*)d_in[9];
    const float* W_hh = (const float*)d_in[10];
    const float* b_hh = (const float*)d_in[11];
    const float* fcW  = (const float*)d_in[12];
    const float* fcb  = (const float*)d_in[13];
    int E = in_sizes[1] / 2;

    float* ws    = (float*)d_ws;
    float* A     = ws;                          // 1024 f
    float* seq   = A + 1024;                    // 262144 f
    float* xp    = seq + 262144;                // 2097152 f
    float* xpart = xp + 2097152;                // 8388608 f
    float* hf32  = xpart + 8388608;             // 16384 f
    float* hb0f  = hf32 + 16384;                // 8192 f  (ushort[16384])
    float* hb1f  = hb0f + 8192;                 // 8192 f
    unsigned short* hb0 = (unsigned short*)hb0f;
    unsigned short* hb1 = (unsigned short*)hb1f;
    unsigned short* Wbf = (unsigned short*)(hb1f + 8192);  // 64M ushort (128 MB)
    // total ~171 MB

    build_adj<<<dim3(1), dim3(256), 0, stream>>>(ei, E, A);
    gcn2_kernel<<<dim3(BT), dim3(256), 0, stream>>>(x, ln_g, ln_b, W1, b1, W2, b2, A, seq);
    xproj_mfma<<<dim3(1024), dim3(256), 0, stream>>>(seq, W_ih, xpart);
    combine_xp<<<dim3(2048), dim3(256), 0, stream>>>(xpart, b_ih, b_hh, xp);
    conv_whh_frag<<<dim3(32768), dim3(256), 0, stream>>>(W_hh, Wbf);

    void* kargs[5];
    kargs[0] = (void*)&Wbf;
    kargs[1] = (void*)&xp;
    kargs[2] = (void*)&hb0;
    kargs[3] = (void*)&hb1;
    kargs[4] = (void*)&hf32;
    hipLaunchCooperativeKernel(lstm_persistent, dim3(256), dim3(512), kargs, 0, stream);

    final_fc<<<dim3(1), dim3(128), 0, stream>>>(hf32, fcW, fcb, (float*)d_out);
}